// Round 6
// baseline (322.904 us; speedup 1.0000x reference)
//
#include <hip/hip_runtime.h>
#include <stdint.h>

#define B_  4
#define S_  2048
#define D_  1024
#define H_  16
#define DK_ 64
#define M_  (B_ * S_)

typedef __attribute__((ext_vector_type(8))) short bf16x8;
typedef __attribute__((ext_vector_type(4))) float f32x4;

// Q pre-scale: 1/sqrt(64) * log2(e)  (scores land in exp2 domain)
#define QSCALE 0.1803368801111204f

__device__ __forceinline__ uint16_t f2bf(float f) {
    uint32_t u = __builtin_bit_cast(uint32_t, f);
    u = (u + 0x7FFFu + ((u >> 16) & 1u)) >> 16;   // round-to-nearest-even
    return (uint16_t)u;
}

// pack two f32 -> bf16x2 (lo in low half), round-half-up, 3 VALU ops
__device__ __forceinline__ uint32_t pk2bf(float hi, float lo) {
    uint32_t a = __builtin_bit_cast(uint32_t, hi) + 0x8000u;
    uint32_t b = __builtin_bit_cast(uint32_t, lo) + 0x8000u;
    return __builtin_amdgcn_perm(a, b, 0x07060302u);
}

// async global->LDS DMA, 16B per lane; lds dst must be wave-uniform base
__device__ __forceinline__ void gl2lds16(const void* g, void* l) {
    __builtin_amdgcn_global_load_lds(
        (const __attribute__((address_space(1))) uint32_t*)g,
        (__attribute__((address_space(3))) uint32_t*)l, 16, 0, 0);
}

// ---------------------------------------------------------------------------
// fp32 -> bf16 elementwise convert, 8 elems/thread
// ---------------------------------------------------------------------------
__global__ __launch_bounds__(256) void cvt_bf16_kernel(const float* __restrict__ in,
                                                       uint16_t* __restrict__ out, int n) {
    int i = (blockIdx.x * 256 + threadIdx.x) * 8;
    if (i >= n) return;
    float4 a = *(const float4*)&in[i];
    float4 b = *(const float4*)&in[i + 4];
    uint16_t o[8] = {f2bf(a.x), f2bf(a.y), f2bf(a.z), f2bf(a.w),
                     f2bf(b.x), f2bf(b.y), f2bf(b.z), f2bf(b.w)};
    *(uint4*)&out[i] = *(const uint4*)o;
}

// ---------------------------------------------------------------------------
// QKV weights fp32 [sel][h][d][dk] -> MFMA-B-fragment-ordered bf16:
// Wtf[(((nb*8+ntg)*32+kb)*64 + lane)*8 + j] = W_sel[h][kb*32+quad*8+j][dk]
//   where nb = sel*8+npair, n = npair*128+ntg*16+ll, h = npair*2+(n>>6), dk=n&63
// ---------------------------------------------------------------------------
__global__ __launch_bounds__(256) void frag_qkv_kernel(
    const float* __restrict__ Wq, const float* __restrict__ Wk,
    const float* __restrict__ Wv, uint16_t* __restrict__ Wtf) {
    const int kb = blockIdx.x;       // 0..31
    const int nb = blockIdx.y;       // 0..23
    const int sel = nb >> 3, npair = nb & 7;
    const float* W = (sel == 0) ? Wq : (sel == 1) ? Wk : Wv;
    const int lane = threadIdx.x & 63, w = threadIdx.x >> 6;
    const int ll = lane & 15, quad = lane >> 4;
    #pragma unroll
    for (int i = 0; i < 2; ++i) {
        const int ntg = w + i * 4;
        const int nl = ntg * 16 + ll;
        const int h = npair * 2 + (nl >> 6), dk = nl & 63;
        const float* src = W + ((size_t)h * 1024 + kb * 32 + quad * 8) * 64 + dk;
        uint16_t tmp[8];
        #pragma unroll
        for (int j = 0; j < 8; ++j) tmp[j] = f2bf(src[(size_t)j * 64]);
        *(uint4*)&Wtf[((((size_t)nb * 8 + ntg) * 32 + kb) * 64 + lane) * 8] = *(const uint4*)tmp;
    }
}

// ---------------------------------------------------------------------------
// Wo fp32 [1024][1024] -> B-fragment-ordered bf16:
// Wof[(((nb2*8+ntg)*32+kb)*64+lane)*8+j] = Wo[kb*32+quad*8+j][nb2*128+ntg*16+ll]
// ---------------------------------------------------------------------------
__global__ __launch_bounds__(256) void frag_wo_kernel(
    const float* __restrict__ Wo, uint16_t* __restrict__ Wof) {
    const int kb = blockIdx.x;       // 0..31
    const int nb2 = blockIdx.y;      // 0..7
    const int lane = threadIdx.x & 63, w = threadIdx.x >> 6;
    const int ll = lane & 15, quad = lane >> 4;
    #pragma unroll
    for (int i = 0; i < 2; ++i) {
        const int ntg = w + i * 4;
        const int n = nb2 * 128 + ntg * 16 + ll;
        const float* src = Wo + (size_t)(kb * 32 + quad * 8) * 1024 + n;
        uint16_t tmp[8];
        #pragma unroll
        for (int j = 0; j < 8; ++j) tmp[j] = f2bf(src[(size_t)j * 1024]);
        *(uint4*)&Wof[((((size_t)nb2 * 8 + ntg) * 32 + kb) * 64 + lane) * 8] = *(const uint4*)tmp;
    }
}

// ---------------------------------------------------------------------------
// QKV projection. Block 128m x 128n, 4 waves 2x2 (64x64/wave), BK=64.
// A staged via global_load_lds into XOR-swizzled [128][64] LDS (16 KB).
// B fragments loaded directly from fragment-ordered Wtf (L2-resident).
// Q pre-scaled by QSCALE. V written TRANSPOSED [bh][dk][s].
// ---------------------------------------------------------------------------
__global__ __launch_bounds__(256) void qkv_mfma_kernel(
    const uint16_t* __restrict__ xb, const uint16_t* __restrict__ Wtf,
    const float* __restrict__ bq, const float* __restrict__ bk, const float* __restrict__ bv,
    uint16_t* __restrict__ Q, uint16_t* __restrict__ K, uint16_t* __restrict__ V)
{
    __shared__ uint16_t As[128 * 64];
    const int tid = threadIdx.x;
    const int nb = blockIdx.x;                  // 0..23
    const int sel = nb >> 3, npair = nb & 7;
    const int m0 = blockIdx.y * 128;
    const int lane = tid & 63, w = tid >> 6;
    const int wr = w >> 1, wc = w & 1;
    const int ll = lane & 15, quad = lane >> 4;
    const float* bias = (sel == 0) ? bq : (sel == 1) ? bk : bv;

    const int sr8 = lane >> 3;              // row offset within 8-row chunk
    const int scb = (lane & 7) ^ sr8;       // logical col-block (XOR swizzle)
    uint16_t* aL = As + (size_t)(w * 4) * 512;

    const size_t bfbase = (size_t)nb * 8 * 32 * 512 + (size_t)lane * 8;

    f32x4 acc[4][4];
    const f32x4 zz = {0.f, 0.f, 0.f, 0.f};
    #pragma unroll
    for (int i = 0; i < 4; ++i)
        #pragma unroll
        for (int j = 0; j < 4; ++j) acc[i][j] = zz;

    for (int k0 = 0; k0 < 1024; k0 += 64) {
        __syncthreads();   // all waves done reading As of prior iter
        #pragma unroll
        for (int i = 0; i < 4; ++i)
            gl2lds16(xb + (size_t)(m0 + w * 32 + i * 8 + sr8) * 1024 + k0 + scb * 8,
                     aL + i * 512);
        // B fragments straight from global (L2)
        bf16x8 bfv[2][4];
        const int kb = k0 >> 5;
        #pragma unroll
        for (int ks = 0; ks < 2; ++ks)
            #pragma unroll
            for (int nt = 0; nt < 4; ++nt)
                bfv[ks][nt] = *(const bf16x8*)&Wtf[bfbase + ((size_t)(wc * 4 + nt) * 32 + kb + ks) * 512];
        __syncthreads();   // drains vmcnt -> A in LDS
        #pragma unroll
        for (int ks = 0; ks < 2; ++ks) {
            bf16x8 af[4];
            #pragma unroll
            for (int mt = 0; mt < 4; ++mt) {
                const int row = wr * 64 + mt * 16 + ll;
                af[mt] = *(const bf16x8*)&As[row * 64 + (((ks * 4 + quad) ^ (ll & 7)) * 8)];
            }
            #pragma unroll
            for (int mt = 0; mt < 4; ++mt)
                #pragma unroll
                for (int nt = 0; nt < 4; ++nt)
                    acc[mt][nt] = __builtin_amdgcn_mfma_f32_16x16x32_bf16(af[mt], bfv[ks][nt], acc[mt][nt], 0, 0, 0);
        }
    }

    if (sel == 2) {
        #pragma unroll
        for (int nt = 0; nt < 4; ++nt) {
            const int nl = wc * 64 + nt * 16 + ll;
            const int hh = npair * 2 + (nl >> 6);
            const int dk = nl & 63;
            const float bval = bias[npair * 128 + nl];
            #pragma unroll
            for (int mt = 0; mt < 4; ++mt) {
                int m = m0 + wr * 64 + mt * 16 + quad * 4;
                int b = m >> 11, s = m & 2047;
                uint2 pv;
                pv.x = pk2bf(acc[mt][nt][1] + bval, acc[mt][nt][0] + bval);
                pv.y = pk2bf(acc[mt][nt][3] + bval, acc[mt][nt][2] + bval);
                *(uint2*)&V[((size_t)(b * 16 + hh) * 64 + dk) * 2048 + s] = pv;
            }
        }
    } else {
        uint16_t* Out = (sel == 0) ? Q : K;
        const float qs = (sel == 0) ? QSCALE : 1.0f;
        #pragma unroll
        for (int nt = 0; nt < 4; ++nt) {
            const int nl = wc * 64 + nt * 16 + ll;
            const int hh = npair * 2 + (nl >> 6);
            const int dk = nl & 63;
            const float bval = bias[npair * 128 + nl];
            #pragma unroll
            for (int mt = 0; mt < 4; ++mt) {
                #pragma unroll
                for (int r = 0; r < 4; ++r) {
                    int m = m0 + wr * 64 + mt * 16 + quad * 4 + r;
                    int b = m >> 11, s = m & 2047;
                    float v = (acc[mt][nt][r] + bval) * qs;
                    Out[((size_t)(b * 16 + hh) * 2048 + s) * 64 + dk] = f2bf(v);
                }
            }
        }
    }
}

// ---------------------------------------------------------------------------
// Flash attention, MFMA, S^T = K·Q^T. One 128-row q-tile per block, grid
// (16, 64) with longest tiles dispatched first. K/V^T staged via
// global_load_lds into XOR-swizzled [64][64] LDS. Ps padded [128][68],
// wave-private (no barrier between write and read). Row-sum via ones-MFMA.
// exp2-domain softmax, no running max (scale folded into Q).
// ---------------------------------------------------------------------------
__global__ __launch_bounds__(256) void attn_mfma_kernel(
    const uint16_t* __restrict__ Q, const uint16_t* __restrict__ K,
    const uint16_t* __restrict__ Vg, uint16_t* __restrict__ CAT)
{
    __shared__ uint16_t Ks[64 * 64];
    __shared__ uint16_t Vt[64 * 64];
    __shared__ __align__(16) uint16_t Ps[128][68];

    const int tid = threadIdx.x;
    const int lane = tid & 63, w = tid >> 6;
    const int ll = lane & 15, quad = lane >> 4;
    const int qtb = 15 - (int)blockIdx.x;   // big q-tiles first
    const int bh = blockIdx.y;
    const int b = bh >> 4, h = bh & 15;

    const uint16_t* Qbh = Q + (size_t)bh * S_ * 64;
    const uint16_t* Kbh = K + (size_t)bh * S_ * 64;
    const uint16_t* Vbh = Vg + (size_t)bh * 64 * S_;   // [dk][s]
    uint16_t* Cbh = CAT + (size_t)b * 2048 * 1024 + h * 64;

    const int q0 = qtb * 128;
    const int qw = q0 + w * 32;     // this wave's q rows [qw, qw+32)

    const int sr8 = lane >> 3;
    const int scb = (lane & 7) ^ sr8;

    // ones B-fragment: B[k][0] = 1 -> row sums land in output col 0
    bf16x8 onesf;
    #pragma unroll
    for (int j = 0; j < 8; ++j) onesf[j] = (ll == 0) ? (short)0x3F80 : (short)0;

    bf16x8 qf[2][2];
    #pragma unroll
    for (int mt = 0; mt < 2; ++mt)
        #pragma unroll
        for (int ks = 0; ks < 2; ++ks)
            qf[mt][ks] = *(const bf16x8*)&Qbh[(size_t)(qw + mt * 16 + ll) * 64 + ks * 32 + quad * 8];

    const f32x4 zz = {0.f, 0.f, 0.f, 0.f};
    f32x4 oacc[2][4];
    f32x4 lacc[2];
    #pragma unroll
    for (int i = 0; i < 2; ++i) {
        lacc[i] = zz;
        #pragma unroll
        for (int j = 0; j < 4; ++j) oacc[i][j] = zz;
    }

    const int ktmax = 2 * qtb + 1;

    for (int kt = 0; kt <= ktmax; ++kt) {
        const int tb = kt * 64;
        __syncthreads();   // all waves done reading Ks/Vt of prior tile
        #pragma unroll
        for (int i = 0; i < 2; ++i) {
            const int c = w * 2 + i;
            const int row = c * 8 + sr8;
            gl2lds16(Kbh + (size_t)(tb + row) * 64 + scb * 8, Ks + (size_t)c * 512);
            gl2lds16(Vbh + (size_t)row * 2048 + tb + scb * 8, Vt + (size_t)c * 512);
        }
        __syncthreads();   // drains vmcnt -> tiles in LDS

        const bool active = (tb <= qw + 31);
        if (active) {
            // S^T = K·Q^T  (M = t rows of K, N = q)
            f32x4 sacc[4][2];
            #pragma unroll
            for (int i = 0; i < 4; ++i)
                #pragma unroll
                for (int j = 0; j < 2; ++j) sacc[i][j] = zz;
            #pragma unroll
            for (int ks = 0; ks < 2; ++ks) {
                #pragma unroll
                for (int tt = 0; tt < 4; ++tt) {
                    const int row = tt * 16 + ll;
                    bf16x8 kf = *(const bf16x8*)&Ks[row * 64 + (((ks * 4 + quad) ^ (ll & 7)) * 8)];
                    #pragma unroll
                    for (int mt = 0; mt < 2; ++mt)
                        sacc[tt][mt] = __builtin_amdgcn_mfma_f32_16x16x32_bf16(kf, qf[mt][ks], sacc[tt][mt], 0, 0, 0);
                }
            }

            // mask + exp2 + pack P into wave-private Ps rows
            const bool needMask = (tb + 63 > qw);
            #pragma unroll
            for (int mt = 0; mt < 2; ++mt) {
                const int qg = qw + mt * 16 + ll;
                #pragma unroll
                for (int tt = 0; tt < 4; ++tt) {
                    #pragma unroll
                    for (int r = 0; r < 4; ++r) {
                        float v = sacc[tt][mt][r];
                        if (needMask) {
                            int tg = tb + tt * 16 + quad * 4 + r;
                            v = (tg > qg) ? -1e30f : v;
                        }
                        sacc[tt][mt][r] = __builtin_amdgcn_exp2f(v);
                    }
                    uint2 pv;
                    pv.x = pk2bf(sacc[tt][mt][1], sacc[tt][mt][0]);
                    pv.y = pk2bf(sacc[tt][mt][3], sacc[tt][mt][2]);
                    *(uint2*)&Ps[w * 32 + mt * 16 + ll][tt * 16 + quad * 4] = pv;
                }
            }

            // O += P·V ; l += P·ones  (Ps rows wave-private; per-wave DS order)
            #pragma unroll
            for (int ks = 0; ks < 2; ++ks) {
                bf16x8 pf[2], vf[4];
                #pragma unroll
                for (int mt = 0; mt < 2; ++mt)
                    pf[mt] = *(const bf16x8*)&Ps[w * 32 + mt * 16 + ll][ks * 32 + quad * 8];
                #pragma unroll
                for (int nt = 0; nt < 4; ++nt) {
                    const int row = nt * 16 + ll;
                    vf[nt] = *(const bf16x8*)&Vt[row * 64 + (((ks * 4 + quad) ^ (ll & 7)) * 8)];
                }
                #pragma unroll
                for (int mt = 0; mt < 2; ++mt) {
                    lacc[mt] = __builtin_amdgcn_mfma_f32_16x16x32_bf16(pf[mt], onesf, lacc[mt], 0, 0, 0);
                    #pragma unroll
                    for (int nt = 0; nt < 4; ++nt)
                        oacc[mt][nt] = __builtin_amdgcn_mfma_f32_16x16x32_bf16(pf[mt], vf[nt], oacc[mt][nt], 0, 0, 0);
                }
            }
        }
    }

    // epilogue: l lives in lanes ll==0 (output col 0); broadcast via shfl
    #pragma unroll
    for (int mt = 0; mt < 2; ++mt) {
        f32x4 li;
        #pragma unroll
        for (int r = 0; r < 4; ++r)
            li[r] = 1.0f / __shfl(lacc[mt][r], lane & 48);
        #pragma unroll
        for (int r = 0; r < 4; ++r) {
            int q = qw + mt * 16 + quad * 4 + r;
            #pragma unroll
            for (int nt = 0; nt < 4; ++nt) {
                float v = oacc[mt][nt][r] * li[r];
                Cbh[(size_t)q * 1024 + nt * 16 + ll] = f2bf(v);
            }
        }
    }
}

// ---------------------------------------------------------------------------
// Output projection: out = CAT(bf16) @ Wo + bo, fp32 out. 128x128 tiles,
// A via global_load_lds (swizzled), B fragments from Wof.
// ---------------------------------------------------------------------------
__global__ __launch_bounds__(256) void oproj_mfma_kernel(
    const uint16_t* __restrict__ CATb, const uint16_t* __restrict__ Wof,
    const float* __restrict__ bo, float* __restrict__ out)
{
    __shared__ uint16_t As[128 * 64];
    const int tid = threadIdx.x;
    const int nb2 = blockIdx.x;                 // n0 = nb2*128
    const int m0 = blockIdx.y * 128;
    const int lane = tid & 63, w = tid >> 6;
    const int wr = w >> 1, wc = w & 1;
    const int ll = lane & 15, quad = lane >> 4;

    const int sr8 = lane >> 3;
    const int scb = (lane & 7) ^ sr8;
    uint16_t* aL = As + (size_t)(w * 4) * 512;

    const size_t bfbase = (size_t)nb2 * 8 * 32 * 512 + (size_t)lane * 8;

    f32x4 acc[4][4];
    const f32x4 zz = {0.f, 0.f, 0.f, 0.f};
    #pragma unroll
    for (int i = 0; i < 4; ++i)
        #pragma unroll
        for (int j = 0; j < 4; ++j) acc[i][j] = zz;

    for (int k0 = 0; k0 < 1024; k0 += 64) {
        __syncthreads();
        #pragma unroll
        for (int i = 0; i < 4; ++i)
            gl2lds16(CATb + (size_t)(m0 + w * 32 + i * 8 + sr8) * 1024 + k0 + scb * 8,
                     aL + i * 512);
        bf16x8 bfv[2][4];
        const int kb = k0 >> 5;
        #pragma unroll
        for (int ks = 0; ks < 2; ++ks)
            #pragma unroll
            for (int nt = 0; nt < 4; ++nt)
                bfv[ks][nt] = *(const bf16x8*)&Wof[bfbase + ((size_t)(wc * 4 + nt) * 32 + kb + ks) * 512];
        __syncthreads();
        #pragma unroll
        for (int ks = 0; ks < 2; ++ks) {
            bf16x8 af[4];
            #pragma unroll
            for (int mt = 0; mt < 4; ++mt) {
                const int row = wr * 64 + mt * 16 + ll;
                af[mt] = *(const bf16x8*)&As[row * 64 + (((ks * 4 + quad) ^ (ll & 7)) * 8)];
            }
            #pragma unroll
            for (int mt = 0; mt < 4; ++mt)
                #pragma unroll
                for (int nt = 0; nt < 4; ++nt)
                    acc[mt][nt] = __builtin_amdgcn_mfma_f32_16x16x32_bf16(af[mt], bfv[ks][nt], acc[mt][nt], 0, 0, 0);
        }
    }

    #pragma unroll
    for (int nt = 0; nt < 4; ++nt) {
        const int nl = wc * 64 + nt * 16 + ll;
        const float bval = bo[nb2 * 128 + nl];
        #pragma unroll
        for (int mt = 0; mt < 4; ++mt) {
            #pragma unroll
            for (int r = 0; r < 4; ++r) {
                int m = m0 + wr * 64 + mt * 16 + quad * 4 + r;
                out[(size_t)m * 1024 + nb2 * 128 + nl] = acc[mt][nt][r] + bval;
            }
        }
    }
}

extern "C" void kernel_launch(void* const* d_in, const int* in_sizes, int n_in,
                              void* d_out, int out_size, void* d_ws, size_t ws_size,
                              hipStream_t stream) {
    const float* x  = (const float*)d_in[0];
    const float* Wq = (const float*)d_in[1];
    const float* bq = (const float*)d_in[2];
    const float* Wk = (const float*)d_in[3];
    const float* bk = (const float*)d_in[4];
    const float* Wv = (const float*)d_in[5];
    const float* bv = (const float*)d_in[6];
    const float* Wo = (const float*)d_in[7];
    const float* bo = (const float*)d_in[8];

    uint8_t* p = (uint8_t*)d_ws;
    uint16_t* xb   = (uint16_t*)p; p += (size_t)M_ * D_ * 2;            // 16 MiB
    uint16_t* Wtf  = (uint16_t*)p; p += (size_t)3 * H_ * DK_ * D_ * 2;  //  6 MiB (fragment-ordered)
    uint16_t* Wof  = (uint16_t*)p; p += (size_t)D_ * D_ * 2;            //  2 MiB (fragment-ordered)
    uint16_t* Qb   = (uint16_t*)p; p += (size_t)B_ * H_ * S_ * DK_ * 2; // 16 MiB
    uint16_t* Kb   = (uint16_t*)p; p += (size_t)B_ * H_ * S_ * DK_ * 2; // 16 MiB
    uint16_t* Vb   = (uint16_t*)p; p += (size_t)B_ * H_ * S_ * DK_ * 2; // 16 MiB (transposed [bh][dk][s])
    uint16_t* CATb = (uint16_t*)p;                                      // 16 MiB

    cvt_bf16_kernel<<<dim3((M_ * D_) / 2048), 256, 0, stream>>>(x, xb, M_ * D_);
    frag_qkv_kernel<<<dim3(32, 24), 256, 0, stream>>>(Wq, Wk, Wv, Wtf);
    frag_wo_kernel<<<dim3(32, 8), 256, 0, stream>>>(Wo, Wof);

    qkv_mfma_kernel<<<dim3(24, M_ / 128), 256, 0, stream>>>(xb, Wtf, bq, bk, bv, Qb, Kb, Vb);
    attn_mfma_kernel<<<dim3(16, B_ * H_), 256, 0, stream>>>(Qb, Kb, Vb, CATb);
    oproj_mfma_kernel<<<dim3(8, M_ / 128), 256, 0, stream>>>(CATb, Wof, bo, (float*)d_out);
}